// Round 11
// baseline (131.948 us; speedup 1.0000x reference)
//
#include <hip/hip_runtime.h>
#include <hip/hip_bf16.h>

// Fused causal MHA: qkv proj -> flash attention (kv-split, 2-deep QK-ahead
// pipeline) -> out proj. B=2 T=2048 D=1024 H=16 hd=64; softmax in log2 domain.

typedef __bf16 bf16;
typedef float f32x4 __attribute__((ext_vector_type(4)));
typedef float f32x16 __attribute__((ext_vector_type(16)));
typedef bf16 bf16x4 __attribute__((ext_vector_type(4)));
typedef bf16 bf16x8 __attribute__((ext_vector_type(8)));

#define B_ 2
#define T_ 2048
#define D_ 1024
#define H_ 16
#define HD_ 64
#define QSPLIT 9  // qt >= QSPLIT gets 2 kv-segments

__device__ __forceinline__ f32x16 mfma32(bf16x8 a, bf16x8 b, f32x16 c) {
    return __builtin_amdgcn_mfma_f32_32x32x16_bf16(a, b, c, 0, 0, 0);
}

// async global->LDS, 16B per lane (wave-uniform LDS base + lane*16)
__device__ __forceinline__ void gload16(void* l, const void* g) {
    __builtin_amdgcn_global_load_lds(
        (const __attribute__((address_space(1))) unsigned int*)g,
        (__attribute__((address_space(3))) unsigned int*)l, 16, 0, 0);
}

__device__ __forceinline__ f32x16 z16() {
    f32x16 v;
#pragma unroll
    for (int i = 0; i < 16; ++i) v[i] = 0.f;
    return v;
}

// ---------------- cast kernels ----------------
__global__ __launch_bounds__(256) void cast_f32_bf16(const float* __restrict__ in,
                                                     bf16* __restrict__ out, int n4) {
    int i = blockIdx.x * 256 + threadIdx.x;
    if (i < n4) {
        float4 v = ((const float4*)in)[i];
        bf16x4 o = { (bf16)v.x, (bf16)v.y, (bf16)v.z, (bf16)v.w };
        ((bf16x4*)out)[i] = o;
    }
}

// in [R][C] f32 -> out [C][R] bf16
__global__ __launch_bounds__(256) void cast_transpose(const float* __restrict__ in,
                                                      bf16* __restrict__ out, int R, int C) {
    __shared__ float tile[32][33];
    int cx = blockIdx.x * 32 + threadIdx.x;
    int r0 = blockIdx.y * 32;
#pragma unroll
    for (int j = 0; j < 32; j += 8)
        tile[threadIdx.y + j][threadIdx.x] = in[(size_t)(r0 + threadIdx.y + j) * C + cx];
    __syncthreads();
    int rx = r0 + threadIdx.x;
    int c0 = blockIdx.x * 32;
#pragma unroll
    for (int j = 0; j < 32; j += 8)
        out[(size_t)(c0 + threadIdx.y + j) * R + rx] = (bf16)tile[threadIdx.x][threadIdx.y + j];
}

// V [bh][T][64] bf16 -> Vt [bh][64][T] bf16 (64x64 tiles, conflict-free LDS)
__global__ __launch_bounds__(256) void transpose_v(const bf16* __restrict__ vb,
                                                   bf16* __restrict__ vt) {
    __shared__ bf16 st[64 * 65];
    const int bh = blockIdx.y;
    const int t0 = blockIdx.x * 64;
    const int tid = threadIdx.x;
#pragma unroll
    for (int c = 0; c < 2; ++c) {
        int cid = tid + c * 256;
        int r = cid >> 3, col = (cid & 7) * 8;
        bf16x8 v = *(const bf16x8*)&vb[((size_t)bh * T_ + t0 + r) * HD_ + col];
#pragma unroll
        for (int j = 0; j < 8; ++j) st[r * 65 + col + j] = v[j];
    }
    __syncthreads();
#pragma unroll
    for (int c = 0; c < 2; ++c) {
        int cid = tid + c * 256;
        int tg = cid & 7, d = cid >> 3;
        bf16x8 o;
#pragma unroll
        for (int j = 0; j < 8; ++j) o[j] = st[(tg * 8 + j) * 65 + d];
        *(bf16x8*)&vt[((size_t)bh * HD_ + d) * T_ + t0 + tg * 8] = o;
    }
}

// ---------------- GEMM: C[M,N] = A[M,K] * Bt[N,K]^T, 32x32x16 MFMA ----------------
template <int MW, int NWN, int EPI>
__global__ __launch_bounds__(256) void gemm_k(
    const bf16* __restrict__ A, const bf16* __restrict__ Bt,
    int M, int N, int K,
    bf16* __restrict__ qb, bf16* __restrict__ kb, bf16* __restrict__ vb,
    const float* __restrict__ bias, float* __restrict__ outf) {
    constexpr int BM = 64 * MW;
    constexpr int BN = 64 * NWN;
    __shared__ bf16 sA[BM * 64];
    __shared__ bf16 sB[BN * 64];
    const int tid = threadIdx.x;
    const int wave = tid >> 6, lane = tid & 63;
    const int ln = lane & 31, hi = lane >> 5;
    const int wr = (wave >> 1) * (32 * MW);
    const int wc = (wave & 1) * (32 * NWN);
    const int m0 = blockIdx.x * BM, n0 = blockIdx.y * BN;

    f32x16 acc[MW][NWN];
#pragma unroll
    for (int mi = 0; mi < MW; ++mi)
#pragma unroll
        for (int ni = 0; ni < NWN; ++ni) acc[mi][ni] = z16();

    for (int k0 = 0; k0 < K; k0 += 64) {
        __syncthreads();
#pragma unroll
        for (int j = 0; j < 2 * MW; ++j) {
            int c = tid + 256 * j;
            int r = c >> 3, g = (c & 7) ^ (r & 7);
            gload16(&sA[c * 8], A + (size_t)(m0 + r) * K + k0 + 8 * g);
        }
#pragma unroll
        for (int j = 0; j < 2 * NWN; ++j) {
            int c = tid + 256 * j;
            int r = c >> 3, g = (c & 7) ^ (r & 7);
            gload16(&sB[c * 8], Bt + (size_t)(n0 + r) * K + k0 + 8 * g);
        }
        __syncthreads();
#pragma unroll
        for (int s = 0; s < 4; ++s) {
            bf16x8 av[MW], bv[NWN];
#pragma unroll
            for (int mi = 0; mi < MW; ++mi) {
                int r = wr + mi * 32 + ln;
                av[mi] = *(const bf16x8*)((const char*)sA + r * 128 +
                                          ((((s << 1) | hi) ^ (r & 7)) << 4));
            }
#pragma unroll
            for (int ni = 0; ni < NWN; ++ni) {
                int r = wc + ni * 32 + ln;
                bv[ni] = *(const bf16x8*)((const char*)sB + r * 128 +
                                          ((((s << 1) | hi) ^ (r & 7)) << 4));
            }
#pragma unroll
            for (int mi = 0; mi < MW; ++mi)
#pragma unroll
                for (int ni = 0; ni < NWN; ++ni)
                    acc[mi][ni] = mfma32(av[mi], bv[ni], acc[mi][ni]);
        }
    }

    // epilogue: C/D layout col=lane&31, row=(r&3)+8*(r>>2)+4*hi
#pragma unroll
    for (int mi = 0; mi < MW; ++mi)
#pragma unroll
        for (int ni = 0; ni < NWN; ++ni)
#pragma unroll
            for (int r = 0; r < 16; ++r) {
                int row = m0 + wr + mi * 32 + (r & 3) + 8 * (r >> 2) + 4 * hi;
                int col = n0 + wc + ni * 32 + ln;
                float v = acc[mi][ni][r];
                if (EPI == 0) {
                    int part = col >> 10, h = (col >> 6) & 15, d = col & 63;
                    int b = row >> 11, t = row & (T_ - 1);
                    size_t idx = ((size_t)(b * H_ + h) * T_ + t) * HD_ + d;
                    bf16* dst = (part == 0) ? qb : (part == 1) ? kb : vb;
                    dst[idx] = (bf16)v;
                } else {
                    outf[(size_t)row * N + col] = v + bias[col];
                }
            }
}

// ---------------- flash attention: 2-deep QK-ahead pipeline ----------------
// Per tile t: DMA(t+2)->bC | QK(t+1)<-bB (MFMA, overlaps softmax VALU below) |
// softmax(t) on pCur | PV(t)<-bA | barrier | rotate. Straight-line macros,
// statically named p-states (rule #20; r9's lambda-by-ref scratch bug avoided).
__device__ __forceinline__ bf16x8 kread(const char* base, int row, int s, int hi) {
    int b = (row * 128 + s * 32 + hi * 16) ^ ((row & 7) << 4);
    return *(const bf16x8*)(base + b);
}
__device__ __forceinline__ bf16x8 vread(const char* base, int row, int s, int hi) {
    int sw = (row & 7) << 4;
    int b0 = (row * 128 + s * 32 + hi * 8) ^ sw;
    int b1 = (row * 128 + s * 32 + hi * 8 + 16) ^ sw;
    bf16x4 lo = *(const bf16x4*)(base + b0);
    bf16x4 hi4 = *(const bf16x4*)(base + b1);
    return __builtin_shufflevector(lo, hi4, 0, 1, 2, 3, 4, 5, 6, 7);
}

__global__ __launch_bounds__(256, 2) void attn_kernel(
    const bf16* __restrict__ qb, const bf16* __restrict__ kb,
    const bf16* __restrict__ vtb, bf16* __restrict__ ob,
    bf16* __restrict__ oP, float2* __restrict__ mlP) {
    __shared__ bf16 sK3[3][4096];  // [64 kv][64 hd], 128B rows, chunk-swizzled
    __shared__ bf16 sV3[3][4096];  // [64 d][64 kv], 128B rows, chunk-swizzled

    const int bid = blockIdx.x;
    const int bh = bid & 31;
    const int sid = bid >> 5;  // 0..22
    int qt, seg, t0, t1;
    if (sid < QSPLIT) {
        qt = sid; seg = -1; t0 = 0; t1 = 2 * qt + 2;
    } else {
        int idx = sid - QSPLIT;
        qt = QSPLIT + (idx >> 1);
        seg = idx & 1;
        if (seg == 0) { t0 = 0; t1 = qt + 1; }
        else          { t0 = qt + 1; t1 = 2 * qt + 2; }
    }
    const int b = bh >> 4, h = bh & 15;
    const int tid = threadIdx.x, wave = tid >> 6, lane = tid & 63;
    const int ln = lane & 31, hi = lane >> 5;
    const int qs = qt * 128 + wave * 32;
    const int qrow = qs + ln;

    const bf16* Qg = qb + (size_t)bh * (T_ * HD_);
    const bf16* Kg = kb + (size_t)bh * (T_ * HD_);
    const bf16* Vtg = vtb + (size_t)bh * (HD_ * T_);

    // Q fragments, scale 0.125*log2(e) folded in (softmax in log2 domain)
    bf16x8 qf[4];
#pragma unroll
    for (int s = 0; s < 4; ++s) {
        bf16x8 v = *(const bf16x8*)&Qg[(size_t)qrow * HD_ + s * 16 + hi * 8];
#pragma unroll
        for (int e = 0; e < 8; ++e) v[e] = (bf16)((float)v[e] * 0.1803368801f);
        qf[s] = v;
    }
    bf16x8 ones;
#pragma unroll
    for (int e = 0; e < 8; ++e) ones[e] = (bf16)1.0f;

    // staging geometry: linear chunk c -> row r=c>>3, source chunk g=(c&7)^(r&7)
    const int rr0 = tid >> 3;
    const int gg = ((tid & 7) ^ (rr0 & 7)) * 8;

#define STAGE(T, BUF)                                                           \
    do {                                                                        \
        int kv0_ = (T) * 64;                                                    \
        gload16(&sK3[BUF][tid * 8], Kg + (size_t)(kv0_ + rr0) * HD_ + gg);      \
        gload16(&sK3[BUF][(tid + 256) * 8],                                     \
                Kg + (size_t)(kv0_ + rr0 + 32) * HD_ + gg);                     \
        gload16(&sV3[BUF][tid * 8], Vtg + (size_t)rr0 * T_ + kv0_ + gg);        \
        gload16(&sV3[BUF][(tid + 256) * 8],                                     \
                Vtg + (size_t)(rr0 + 32) * T_ + kv0_ + gg);                     \
    } while (0)

#define QK_STEP(BUFK, PN0, PN1)                                                 \
    do {                                                                        \
        const char* kbase_ = (const char*)sK3[BUFK];                            \
        f32x16 q0_ = z16(), q1_ = z16();                                        \
        __builtin_amdgcn_s_setprio(1);                                          \
        _Pragma("unroll") for (int s_ = 0; s_ < 4; ++s_) {                      \
            q0_ = mfma32(kread(kbase_, ln, s_, hi), qf[s_], q0_);               \
            q1_ = mfma32(kread(kbase_, ln + 32, s_, hi), qf[s_], q1_);          \
        }                                                                       \
        __builtin_amdgcn_s_setprio(0);                                          \
        PN0 = q0_;                                                              \
        PN1 = q1_;                                                              \
    } while (0)

#define SM_PV(T, PC0, PC1)                                                      \
    do {                                                                        \
        if (64 * (T) + 63 > qs) { /* diagonal/future tile: causal mask */       \
            int kvb_ = 64 * (T) + 4 * hi;                                       \
            _Pragma("unroll") for (int r_ = 0; r_ < 16; ++r_) {                 \
                int kvr_ = kvb_ + (r_ & 3) + 8 * (r_ >> 2);                     \
                if (kvr_ > qrow) PC0[r_] = NINF;                                \
                if (kvr_ + 32 > qrow) PC1[r_] = NINF;                           \
            }                                                                   \
        }                                                                       \
        float mx0_ = NINF, mx1_ = NINF, mx2_ = NINF, mx3_ = NINF;               \
        _Pragma("unroll") for (int r_ = 0; r_ < 16; r_ += 4) {                  \
            mx0_ = fmaxf(fmaxf(PC0[r_], PC1[r_]), mx0_);                        \
            mx1_ = fmaxf(fmaxf(PC0[r_ + 1], PC1[r_ + 1]), mx1_);                \
            mx2_ = fmaxf(fmaxf(PC0[r_ + 2], PC1[r_ + 2]), mx2_);                \
            mx3_ = fmaxf(fmaxf(PC0[r_ + 3], PC1[r_ + 3]), mx3_);                \
        }                                                                       \
        float pm_ = fmaxf(fmaxf(mx0_, mx1_), fmaxf(mx2_, mx3_));                \
        /* half-local pm; wave-wide __any covers both halves; reconcile only */ \
        /* on trigger (rare with defer-8) -> no per-tile shfl */                \
        if (__any(pm_ > mR + 8.f)) {                                            \
            float pmw_ = fmaxf(pm_, __shfl_xor(pm_, 32));                       \
            float mnew_ = fmaxf(mR, pmw_);                                      \
            float fac_ = exp2f(mR - mnew_);                                     \
            lR *= fac_;                                                         \
            _Pragma("unroll") for (int r_ = 0; r_ < 16; ++r_) {                 \
                oA[r_] *= fac_;                                                 \
                oB[r_] *= fac_;                                                 \
            }                                                                   \
            mR = mnew_;                                                         \
        }                                                                       \
        bf16x8 pa0_, pa1_, pa2_, pa3_;                                          \
        _Pragma("unroll") for (int e_ = 0; e_ < 8; ++e_) {                      \
            pa0_[e_] = (bf16)exp2f(PC0[e_] - mR);                               \
            pa1_[e_] = (bf16)exp2f(PC0[8 + e_] - mR);                           \
            pa2_[e_] = (bf16)exp2f(PC1[e_] - mR);                               \
            pa3_[e_] = (bf16)exp2f(PC1[8 + e_] - mR);                           \
        }                                                                       \
        const char* vbase_ = (const char*)sV3[bA];                              \
        __builtin_amdgcn_s_setprio(1);                                          \
        f32x16 sacc_ = mfma32(ones, pa0_, z16());                               \
        sacc_ = mfma32(ones, pa1_, sacc_);                                      \
        sacc_ = mfma32(ones, pa2_, sacc_);                                      \
        sacc_ = mfma32(ones, pa3_, sacc_);                                      \
        oA = mfma32(vread(vbase_, ln, 0, hi), pa0_, oA);                        \
        oB = mfma32(vread(vbase_, ln + 32, 0, hi), pa0_, oB);                   \
        oA = mfma32(vread(vbase_, ln, 1, hi), pa1_, oA);                        \
        oB = mfma32(vread(vbase_, ln + 32, 1, hi), pa1_, oB);                   \
        oA = mfma32(vread(vbase_, ln, 2, hi), pa2_, oA);                        \
        oB = mfma32(vread(vbase_, ln + 32, 2, hi), pa2_, oB);                   \
        oA = mfma32(vread(vbase_, ln, 3, hi), pa3_, oA);                        \
        oB = mfma32(vread(vbase_, ln + 32, 3, hi), pa3_, oB);                   \
        __builtin_amdgcn_s_setprio(0);                                          \
        lR += sacc_[0];                                                         \
    } while (0)

#define BODY(T, PC0, PC1, PN0, PN1)                                             \
    do {                                                                        \
        if ((T) + 2 < t1) STAGE((T) + 2, bC);                                   \
        if ((T) + 1 < t1) QK_STEP(bB, PN0, PN1);                                \
        SM_PV(T, PC0, PC1);                                                     \
        __syncthreads();                                                        \
        int tmp_ = bA;                                                          \
        bA = bB;                                                                \
        bB = bC;                                                                \
        bC = tmp_;                                                              \
    } while (0)

    const float NINF = -__builtin_inff();
    f32x16 oA = z16(), oB = z16();
    float mR = NINF, lR = 0.f;
    int bA = 0, bB = 1, bC = 2;

    // prologue: buf0 = tile t0; buf1 = tile t0+1 (DMA); pE = QK(t0)
    STAGE(t0, 0);
    __syncthreads();
    if (t0 + 1 < t1) STAGE(t0 + 1, 1);
    f32x16 pE0, pE1, pO0, pO1;
    QK_STEP(0, pE0, pE1);
    __syncthreads();

    int t = t0;
    for (; t + 1 < t1; t += 2) {
        BODY(t, pE0, pE1, pO0, pO1);
        BODY(t + 1, pO0, pO1, pE0, pE1);
    }
    if (t < t1) {
        BODY(t, pE0, pE1, pO0, pO1);
    }

    if (seg < 0) {
        // final: normalized write to ob [B][T][H*64]
        float inv = 1.f / lR;
        bf16* orow = ob + ((size_t)(b * T_ + qrow)) * D_ + h * HD_;
#pragma unroll
        for (int g = 0; g < 4; ++g) {
            bf16x4 w, w2;
#pragma unroll
            for (int j = 0; j < 4; ++j) {
                w[j] = (bf16)(oA[4 * g + j] * inv);
                w2[j] = (bf16)(oB[4 * g + j] * inv);
            }
            *(bf16x4*)&orow[4 * hi + 8 * g] = w;
            *(bf16x4*)&orow[32 + 4 * hi + 8 * g] = w2;
        }
    } else {
        // partial: unnormalized O + (m,l); m must be wave-consistent -> pair-max
        float mW = fmaxf(mR, __shfl_xor(mR, 32));
        if (mW != mR) {  // reconcile (no-op in practice: mR is pair-uniform)
            float fac = exp2f(mR - mW);
            lR *= fac;
#pragma unroll
            for (int r = 0; r < 16; ++r) { oA[r] *= fac; oB[r] *= fac; }
            mR = mW;
        }
        int row = wave * 32 + ln;
        size_t sbase = (((size_t)bh * (16 - QSPLIT) + (qt - QSPLIT)) * 2 + seg);
        bf16* prow = oP + (sbase * 128 + row) * 64;
#pragma unroll
        for (int g = 0; g < 4; ++g) {
            bf16x4 w, w2;
#pragma unroll
            for (int j = 0; j < 4; ++j) {
                w[j] = (bf16)oA[4 * g + j];
                w2[j] = (bf16)oB[4 * g + j];
            }
            *(bf16x4*)&prow[4 * hi + 8 * g] = w;
            *(bf16x4*)&prow[32 + 4 * hi + 8 * g] = w2;
        }
        if (hi == 0) mlP[sbase * 128 + row] = make_float2(mR, lR);
    }
#undef STAGE
#undef QK_STEP
#undef SM_PV
#undef BODY
}

// merge 2 kv-segments per split q-strip: one thread per q-row
__global__ __launch_bounds__(256) void attn_merge(
    const bf16* __restrict__ oP, const float2* __restrict__ mlP,
    bf16* __restrict__ ob) {
    constexpr int NQS = 16 - QSPLIT;  // 7
    int gid = blockIdx.x * 256 + threadIdx.x;  // 32*NQS*128 total
    int bh = gid / (NQS * 128);
    int rem = gid - bh * (NQS * 128);
    int qi = rem >> 7, row = rem & 127;
    int b = bh >> 4, h = bh & 15;
    int t = (QSPLIT + qi) * 128 + row;
    size_t sbase = ((size_t)bh * NQS + qi) * 2;
    float2 ml0 = mlP[(sbase + 0) * 128 + row];
    float2 ml1 = mlP[(sbase + 1) * 128 + row];
    float ms = fmaxf(ml0.x, ml1.x);
    float w0 = exp2f(ml0.x - ms), w1 = exp2f(ml1.x - ms);
    float inv = 1.f / (ml0.y * w0 + ml1.y * w1);
    w0 *= inv; w1 *= inv;
    const bf16* r0 = oP + ((sbase + 0) * 128 + row) * 64;
    const bf16* r1 = oP + ((sbase + 1) * 128 + row) * 64;
    bf16* dst = ob + ((size_t)(b * T_ + t)) * D_ + h * HD_;
#pragma unroll
    for (int g = 0; g < 8; ++g) {
        bf16x8 a = *(const bf16x8*)&r0[g * 8];
        bf16x8 c = *(const bf16x8*)&r1[g * 8];
        bf16x8 o;
#pragma unroll
        for (int j = 0; j < 8; ++j)
            o[j] = (bf16)((float)a[j] * w0 + (float)c[j] * w1);
        *(bf16x8*)&dst[g * 8] = o;
    }
}

// ---------------- launch ----------------
extern "C" void kernel_launch(void* const* d_in, const int* in_sizes, int n_in,
                              void* d_out, int out_size, void* d_ws, size_t ws_size,
                              hipStream_t stream) {
    const float* x = (const float*)d_in[0];
    const float* w_qkv = (const float*)d_in[1];
    const float* w_proj = (const float*)d_in[2];
    const float* b_proj = (const float*)d_in[3];
    float* out = (float*)d_out;
    char* ws = (char*)d_ws;

    // ws layout (40 MB total, aliased by liveness):
    bf16* xb = (bf16*)(ws);                 // [4096][1024]  8MB ; dead after GEMM1
    bf16* ob = (bf16*)(ws);                 // alias: attn out (written after xb dead)
    bf16* wqkvt = (bf16*)(ws + 8388608);    // [3072][1024]  6MB ; dead after GEMM1
    bf16* vtbuf = (bf16*)(ws + 8388608);    // alias: [bh][64][T] 8MB
    bf16* qbuf = (bf16*)(ws + 16777216);    // [bh][T][64]   8MB
    bf16* wprojt = (bf16*)(ws + 16777216);  // alias: [1024][1024] 2MB (after attn)
    bf16* kbuf = (bf16*)(ws + 25165824);    // [bh][T][64]   8MB
    bf16* vbuf = (bf16*)(ws + 33554432);    // [bh][T][64]   8MB ; dead after transpose_v
    bf16* oP = (bf16*)(ws + 33554432);      // alias: partial O [32][7][2][128][64] 7.34MB
    float2* mlP = (float2*)(ws + 33554432 + 7340032);  // [32][7][2][128] 448KB

    cast_f32_bf16<<<4096, 256, 0, stream>>>(x, xb, (B_ * T_ * D_) / 4);
    dim3 tb(32, 8);
    cast_transpose<<<dim3(3 * D_ / 32, D_ / 32), tb, 0, stream>>>(w_qkv, wqkvt, D_, 3 * D_);

    // GEMM1: 4096 x 3072 x 1024, block 128x128 -> grid 768 = 3 blocks/CU
    gemm_k<2, 2, 0><<<dim3((B_ * T_) / 128, (3 * D_) / 128), 256, 0, stream>>>(
        xb, wqkvt, B_ * T_, 3 * D_, D_, qbuf, kbuf, vbuf, nullptr, nullptr);

    transpose_v<<<dim3(T_ / 64, B_ * H_), 256, 0, stream>>>(vbuf, vtbuf);

    // attn: per bh 9 single-strips + 7*2 split segments = 23 blocks; x32 bh = 736
    attn_kernel<<<23 * 32, 256, 0, stream>>>(qbuf, kbuf, vtbuf, ob, oP, mlP);
    // merge: 32*7*128 rows / 256 = 112 blocks
    attn_merge<<<112, 256, 0, stream>>>(oP, mlP, ob);

    cast_transpose<<<dim3(D_ / 32, D_ / 32), tb, 0, stream>>>(w_proj, wprojt, D_, D_);

    // GEMM2: 4096 x 1024 x 1024, block 64x128 -> grid 512 = 2 blocks/CU
    gemm_k<1, 2, 1><<<dim3((B_ * T_) / 64, D_ / 128), 256, 0, stream>>>(
        ob, wprojt, B_ * T_, D_, D_, nullptr, nullptr, nullptr, b_proj, out);
}

// Round 12
// 126.482 us; speedup vs baseline: 1.0432x; 1.0432x over previous
//
#include <hip/hip_runtime.h>
#include <hip/hip_bf16.h>

// Fused causal MHA: qkv proj -> flash attention (kv-split, counted-vmcnt
// 3-buffer pipeline) -> out proj. B=2 T=2048 D=1024 H=16 hd=64.

typedef __bf16 bf16;
typedef float f32x4 __attribute__((ext_vector_type(4)));
typedef float f32x16 __attribute__((ext_vector_type(16)));
typedef bf16 bf16x4 __attribute__((ext_vector_type(4)));
typedef bf16 bf16x8 __attribute__((ext_vector_type(8)));

#define B_ 2
#define T_ 2048
#define D_ 1024
#define H_ 16
#define HD_ 64
#define QSPLIT 9  // qt >= QSPLIT gets 2 kv-segments

__device__ __forceinline__ f32x16 mfma32(bf16x8 a, bf16x8 b, f32x16 c) {
    return __builtin_amdgcn_mfma_f32_32x32x16_bf16(a, b, c, 0, 0, 0);
}

// async global->LDS, 16B per lane (wave-uniform LDS base + lane*16)
__device__ __forceinline__ void gload16(void* l, const void* g) {
    __builtin_amdgcn_global_load_lds(
        (const __attribute__((address_space(1))) unsigned int*)g,
        (__attribute__((address_space(3))) unsigned int*)l, 16, 0, 0);
}

__device__ __forceinline__ f32x16 z16() {
    f32x16 v;
#pragma unroll
    for (int i = 0; i < 16; ++i) v[i] = 0.f;
    return v;
}

// ---------------- cast kernels ----------------
__global__ __launch_bounds__(256) void cast_f32_bf16(const float* __restrict__ in,
                                                     bf16* __restrict__ out, int n4) {
    int i = blockIdx.x * 256 + threadIdx.x;
    if (i < n4) {
        float4 v = ((const float4*)in)[i];
        bf16x4 o = { (bf16)v.x, (bf16)v.y, (bf16)v.z, (bf16)v.w };
        ((bf16x4*)out)[i] = o;
    }
}

// in [R][C] f32 -> out [C][R] bf16
__global__ __launch_bounds__(256) void cast_transpose(const float* __restrict__ in,
                                                      bf16* __restrict__ out, int R, int C) {
    __shared__ float tile[32][33];
    int cx = blockIdx.x * 32 + threadIdx.x;
    int r0 = blockIdx.y * 32;
#pragma unroll
    for (int j = 0; j < 32; j += 8)
        tile[threadIdx.y + j][threadIdx.x] = in[(size_t)(r0 + threadIdx.y + j) * C + cx];
    __syncthreads();
    int rx = r0 + threadIdx.x;
    int c0 = blockIdx.x * 32;
#pragma unroll
    for (int j = 0; j < 32; j += 8)
        out[(size_t)(c0 + threadIdx.y + j) * R + rx] = (bf16)tile[threadIdx.x][threadIdx.y + j];
}

// V [bh][T][64] bf16 -> Vt [bh][64][T] bf16 (64x64 tiles, conflict-free LDS)
__global__ __launch_bounds__(256) void transpose_v(const bf16* __restrict__ vb,
                                                   bf16* __restrict__ vt) {
    __shared__ bf16 st[64 * 65];
    const int bh = blockIdx.y;
    const int t0 = blockIdx.x * 64;
    const int tid = threadIdx.x;
#pragma unroll
    for (int c = 0; c < 2; ++c) {
        int cid = tid + c * 256;
        int r = cid >> 3, col = (cid & 7) * 8;
        bf16x8 v = *(const bf16x8*)&vb[((size_t)bh * T_ + t0 + r) * HD_ + col];
#pragma unroll
        for (int j = 0; j < 8; ++j) st[r * 65 + col + j] = v[j];
    }
    __syncthreads();
#pragma unroll
    for (int c = 0; c < 2; ++c) {
        int cid = tid + c * 256;
        int tg = cid & 7, d = cid >> 3;
        bf16x8 o;
#pragma unroll
        for (int j = 0; j < 8; ++j) o[j] = st[(tg * 8 + j) * 65 + d];
        *(bf16x8*)&vt[((size_t)bh * HD_ + d) * T_ + t0 + tg * 8] = o;
    }
}

// ---------------- GEMM: C[M,N] = A[M,K] * Bt[N,K]^T, 32x32x16 MFMA ----------------
template <int MW, int NWN, int EPI>
__global__ __launch_bounds__(256) void gemm_k(
    const bf16* __restrict__ A, const bf16* __restrict__ Bt,
    int M, int N, int K,
    bf16* __restrict__ qb, bf16* __restrict__ kb, bf16* __restrict__ vb,
    const float* __restrict__ bias, float* __restrict__ outf) {
    constexpr int BM = 64 * MW;
    constexpr int BN = 64 * NWN;
    __shared__ bf16 sA[BM * 64];
    __shared__ bf16 sB[BN * 64];
    const int tid = threadIdx.x;
    const int wave = tid >> 6, lane = tid & 63;
    const int ln = lane & 31, hi = lane >> 5;
    const int wr = (wave >> 1) * (32 * MW);
    const int wc = (wave & 1) * (32 * NWN);
    const int m0 = blockIdx.x * BM, n0 = blockIdx.y * BN;

    f32x16 acc[MW][NWN];
#pragma unroll
    for (int mi = 0; mi < MW; ++mi)
#pragma unroll
        for (int ni = 0; ni < NWN; ++ni) acc[mi][ni] = z16();

    for (int k0 = 0; k0 < K; k0 += 64) {
        __syncthreads();
#pragma unroll
        for (int j = 0; j < 2 * MW; ++j) {
            int c = tid + 256 * j;
            int r = c >> 3, g = (c & 7) ^ (r & 7);
            gload16(&sA[c * 8], A + (size_t)(m0 + r) * K + k0 + 8 * g);
        }
#pragma unroll
        for (int j = 0; j < 2 * NWN; ++j) {
            int c = tid + 256 * j;
            int r = c >> 3, g = (c & 7) ^ (r & 7);
            gload16(&sB[c * 8], Bt + (size_t)(n0 + r) * K + k0 + 8 * g);
        }
        __syncthreads();
#pragma unroll
        for (int s = 0; s < 4; ++s) {
            bf16x8 av[MW], bv[NWN];
#pragma unroll
            for (int mi = 0; mi < MW; ++mi) {
                int r = wr + mi * 32 + ln;
                av[mi] = *(const bf16x8*)((const char*)sA + r * 128 +
                                          ((((s << 1) | hi) ^ (r & 7)) << 4));
            }
#pragma unroll
            for (int ni = 0; ni < NWN; ++ni) {
                int r = wc + ni * 32 + ln;
                bv[ni] = *(const bf16x8*)((const char*)sB + r * 128 +
                                          ((((s << 1) | hi) ^ (r & 7)) << 4));
            }
#pragma unroll
            for (int mi = 0; mi < MW; ++mi)
#pragma unroll
                for (int ni = 0; ni < NWN; ++ni)
                    acc[mi][ni] = mfma32(av[mi], bv[ni], acc[mi][ni]);
        }
    }

    // epilogue: C/D layout col=lane&31, row=(r&3)+8*(r>>2)+4*hi
#pragma unroll
    for (int mi = 0; mi < MW; ++mi)
#pragma unroll
        for (int ni = 0; ni < NWN; ++ni)
#pragma unroll
            for (int r = 0; r < 16; ++r) {
                int row = m0 + wr + mi * 32 + (r & 3) + 8 * (r >> 2) + 4 * hi;
                int col = n0 + wc + ni * 32 + ln;
                float v = acc[mi][ni][r];
                if (EPI == 0) {
                    int part = col >> 10, h = (col >> 6) & 15, d = col & 63;
                    int b = row >> 11, t = row & (T_ - 1);
                    size_t idx = ((size_t)(b * H_ + h) * T_ + t) * HD_ + d;
                    bf16* dst = (part == 0) ? qb : (part == 1) ? kb : vb;
                    dst[idx] = (bf16)v;
                } else {
                    outf[(size_t)row * N + col] = v + bias[col];
                }
            }
}

// ---------------- flash attention: counted-vmcnt 3-buffer pipeline ----------
// r10 body (best measured) + T3/T4: raw s_barrier (no vmcnt(0) drain) with
// counted s_waitcnt vmcnt(4) -> prefetch loads genuinely cross barriers.
// Invariant at loop top: tile t's DMA complete block-wide (each wave waited
// vmcnt before the barrier); tile t+1 in flight; t+2 staged this iteration.
__device__ __forceinline__ bf16x8 kread(const char* base, int row, int s, int hi) {
    int b = (row * 128 + s * 32 + hi * 16) ^ ((row & 7) << 4);
    return *(const bf16x8*)(base + b);
}
__device__ __forceinline__ bf16x8 vread(const char* base, int row, int s, int hi) {
    int sw = (row & 7) << 4;
    int b0 = (row * 128 + s * 32 + hi * 8) ^ sw;
    int b1 = (row * 128 + s * 32 + hi * 8 + 16) ^ sw;
    bf16x4 lo = *(const bf16x4*)(base + b0);
    bf16x4 hi4 = *(const bf16x4*)(base + b1);
    return __builtin_shufflevector(lo, hi4, 0, 1, 2, 3, 4, 5, 6, 7);
}

__global__ __launch_bounds__(256, 3) void attn_kernel(
    const bf16* __restrict__ qb, const bf16* __restrict__ kb,
    const bf16* __restrict__ vtb, bf16* __restrict__ ob,
    bf16* __restrict__ oP, float2* __restrict__ mlP) {
    __shared__ bf16 sK3[3][4096];  // [64 kv][64 hd], 128B rows, chunk-swizzled
    __shared__ bf16 sV3[3][4096];  // [64 d][64 kv], 128B rows, chunk-swizzled

    const int bid = blockIdx.x;
    const int bh = bid & 31;
    const int sid = bid >> 5;  // 0..22
    int qt, seg, t0, t1;
    if (sid < QSPLIT) {
        qt = sid; seg = -1; t0 = 0; t1 = 2 * qt + 2;
    } else {
        int idx = sid - QSPLIT;
        qt = QSPLIT + (idx >> 1);
        seg = idx & 1;
        if (seg == 0) { t0 = 0; t1 = qt + 1; }
        else          { t0 = qt + 1; t1 = 2 * qt + 2; }
    }
    const int b = bh >> 4, h = bh & 15;
    const int tid = threadIdx.x, wave = tid >> 6, lane = tid & 63;
    const int ln = lane & 31, hi = lane >> 5;
    const int qs = qt * 128 + wave * 32;
    const int qrow = qs + ln;

    const bf16* Qg = qb + (size_t)bh * (T_ * HD_);
    const bf16* Kg = kb + (size_t)bh * (T_ * HD_);
    const bf16* Vtg = vtb + (size_t)bh * (HD_ * T_);

    // Q fragments, scale 0.125*log2(e) folded in (softmax in log2 domain)
    bf16x8 qf[4];
#pragma unroll
    for (int s = 0; s < 4; ++s) {
        bf16x8 v = *(const bf16x8*)&Qg[(size_t)qrow * HD_ + s * 16 + hi * 8];
#pragma unroll
        for (int e = 0; e < 8; ++e) v[e] = (bf16)((float)v[e] * 0.1803368801f);
        qf[s] = v;
    }
    bf16x8 ones;
#pragma unroll
    for (int e = 0; e < 8; ++e) ones[e] = (bf16)1.0f;

    // staging geometry: linear chunk c -> row r=c>>3, source chunk g=(c&7)^(r&7)
    const int rr0 = tid >> 3;
    const int gg = ((tid & 7) ^ (rr0 & 7)) * 8;

#define STAGE(T, BUF)                                                           \
    do {                                                                        \
        int kv0_ = (T) * 64;                                                    \
        gload16(&sK3[BUF][tid * 8], Kg + (size_t)(kv0_ + rr0) * HD_ + gg);      \
        gload16(&sK3[BUF][(tid + 256) * 8],                                     \
                Kg + (size_t)(kv0_ + rr0 + 32) * HD_ + gg);                     \
        gload16(&sV3[BUF][tid * 8], Vtg + (size_t)rr0 * T_ + kv0_ + gg);        \
        gload16(&sV3[BUF][(tid + 256) * 8],                                     \
                Vtg + (size_t)(rr0 + 32) * T_ + kv0_ + gg);                     \
    } while (0)

    // prologue: stage t0 -> b0, t0+1 -> b1; drain so t0 is complete, t0+1 in flight
    STAGE(t0, 0);
    if (t0 + 1 < t1) {
        STAGE(t0 + 1, 1);
        asm volatile("s_waitcnt vmcnt(4)" ::: "memory");
    } else {
        asm volatile("s_waitcnt vmcnt(0)" ::: "memory");
    }
    __builtin_amdgcn_sched_barrier(0);
    __builtin_amdgcn_s_barrier();
    __builtin_amdgcn_sched_barrier(0);

    const float NINF = -__builtin_inff();
    f32x16 oA = z16(), oB = z16();
    float mR = NINF, lR = 0.f;
    int bA = 0, bB = 1, bC = 2;  // bA: tile t; bB: tile t+1; bC: DMA target (t+2)

    for (int t = t0; t < t1; ++t) {
        if (t + 2 < t1) STAGE(t + 2, bC);  // issue early; crosses this iter's barrier

        if (64 * t <= qs + 31) {  // wave not fully masked for this tile
            const char* kbase = (const char*)sK3[bA];
            const char* vbase = (const char*)sV3[bA];

            f32x16 p0 = z16(), p1 = z16();
            __builtin_amdgcn_s_setprio(1);
#pragma unroll
            for (int s = 0; s < 4; ++s) {
                bf16x8 a0 = kread(kbase, ln, s, hi);
                bf16x8 a1 = kread(kbase, ln + 32, s, hi);
                p0 = mfma32(a0, qf[s], p0);
                p1 = mfma32(a1, qf[s], p1);
            }
            __builtin_amdgcn_s_setprio(0);

            if (64 * t + 63 > qs) {  // diagonal tile: causal mask
                int kvb = 64 * t + 4 * hi;
#pragma unroll
                for (int r = 0; r < 16; ++r) {
                    int kvr = kvb + (r & 3) + 8 * (r >> 2);
                    if (kvr > qrow) p0[r] = NINF;
                    if (kvr + 32 > qrow) p1[r] = NINF;
                }
            }

            // max reduce: max3-shaped (16 fused ops)
            float mx0 = NINF, mx1 = NINF, mx2 = NINF, mx3 = NINF;
#pragma unroll
            for (int r = 0; r < 16; r += 4) {
                mx0 = fmaxf(fmaxf(p0[r], p1[r]), mx0);
                mx1 = fmaxf(fmaxf(p0[r + 1], p1[r + 1]), mx1);
                mx2 = fmaxf(fmaxf(p0[r + 2], p1[r + 2]), mx2);
                mx3 = fmaxf(fmaxf(p0[r + 3], p1[r + 3]), mx3);
            }
            float pm = fmaxf(fmaxf(mx0, mx1), fmaxf(mx2, mx3));
            pm = fmaxf(pm, __shfl_xor(pm, 32));

            // T13 defer-max: rescale only when the running max grows materially
            if (__any(pm > mR + 8.f)) {
                float mnew = fmaxf(mR, pm);
                float fac = exp2f(mR - mnew);
                lR *= fac;
#pragma unroll
                for (int r = 0; r < 16; ++r) { oA[r] *= fac; oB[r] *= fac; }
                mR = mnew;
            }

            // exp2 -> bf16 pack (row-sum via ones-MFMA below)
            bf16x8 pa0, pa1, pa2, pa3;
#pragma unroll
            for (int e = 0; e < 8; ++e) {
                pa0[e] = (bf16)exp2f(p0[e] - mR);
                pa1[e] = (bf16)exp2f(p0[8 + e] - mR);
                pa2[e] = (bf16)exp2f(p1[e] - mR);
                pa3[e] = (bf16)exp2f(p1[8 + e] - mR);
            }

            __builtin_amdgcn_s_setprio(1);
            // row-sum: D = ones * P^T -> every D row = column sums of P
            f32x16 sacc = mfma32(ones, pa0, z16());
            sacc = mfma32(ones, pa1, sacc);
            sacc = mfma32(ones, pa2, sacc);
            sacc = mfma32(ones, pa3, sacc);
#pragma unroll
            for (int s = 0; s < 4; ++s) {
                bf16x8 pas = (s == 0) ? pa0 : (s == 1) ? pa1 : (s == 2) ? pa2 : pa3;
                oA = mfma32(vread(vbase, ln, s, hi), pas, oA);
                oB = mfma32(vread(vbase, ln + 32, s, hi), pas, oB);
            }
            __builtin_amdgcn_s_setprio(0);
            lR += sacc[0];  // full 64-kv row sum (MFMA reduced across wave)
        }

        if (t + 1 < t1) {
            // wait for t+1's loads (issued last iter); leave t+2's in flight
            if (t + 2 < t1) {
                asm volatile("s_waitcnt vmcnt(4)" ::: "memory");
            } else {
                asm volatile("s_waitcnt vmcnt(0)" ::: "memory");
            }
            __builtin_amdgcn_sched_barrier(0);
            __builtin_amdgcn_s_barrier();  // raw: no vmcnt(0) drain
            __builtin_amdgcn_sched_barrier(0);
        }
        int tmp = bA; bA = bB; bB = bC; bC = tmp;
    }
#undef STAGE

    if (seg < 0) {
        // final: normalized write to ob [B][T][H*64]
        float inv = 1.f / lR;
        bf16* orow = ob + ((size_t)(b * T_ + qrow)) * D_ + h * HD_;
#pragma unroll
        for (int g = 0; g < 4; ++g) {
            bf16x4 w, w2;
#pragma unroll
            for (int j = 0; j < 4; ++j) {
                w[j] = (bf16)(oA[4 * g + j] * inv);
                w2[j] = (bf16)(oB[4 * g + j] * inv);
            }
            *(bf16x4*)&orow[4 * hi + 8 * g] = w;
            *(bf16x4*)&orow[32 + 4 * hi + 8 * g] = w2;
        }
    } else {
        // partial: unnormalized O + (m,l)
        int row = wave * 32 + ln;
        size_t sbase = (((size_t)bh * (16 - QSPLIT) + (qt - QSPLIT)) * 2 + seg);
        bf16* prow = oP + (sbase * 128 + row) * 64;
#pragma unroll
        for (int g = 0; g < 4; ++g) {
            bf16x4 w, w2;
#pragma unroll
            for (int j = 0; j < 4; ++j) {
                w[j] = (bf16)oA[4 * g + j];
                w2[j] = (bf16)oB[4 * g + j];
            }
            *(bf16x4*)&prow[4 * hi + 8 * g] = w;
            *(bf16x4*)&prow[32 + 4 * hi + 8 * g] = w2;
        }
        if (hi == 0) mlP[sbase * 128 + row] = make_float2(mR, lR);
    }
}

// merge 2 kv-segments per split q-strip: one thread per q-row
__global__ __launch_bounds__(256) void attn_merge(
    const bf16* __restrict__ oP, const float2* __restrict__ mlP,
    bf16* __restrict__ ob) {
    constexpr int NQS = 16 - QSPLIT;  // 7
    int gid = blockIdx.x * 256 + threadIdx.x;  // 32*NQS*128 total
    int bh = gid / (NQS * 128);
    int rem = gid - bh * (NQS * 128);
    int qi = rem >> 7, row = rem & 127;
    int b = bh >> 4, h = bh & 15;
    int t = (QSPLIT + qi) * 128 + row;
    size_t sbase = ((size_t)bh * NQS + qi) * 2;
    float2 ml0 = mlP[(sbase + 0) * 128 + row];
    float2 ml1 = mlP[(sbase + 1) * 128 + row];
    float ms = fmaxf(ml0.x, ml1.x);
    float w0 = exp2f(ml0.x - ms), w1 = exp2f(ml1.x - ms);
    float inv = 1.f / (ml0.y * w0 + ml1.y * w1);
    w0 *= inv; w1 *= inv;
    const bf16* r0 = oP + ((sbase + 0) * 128 + row) * 64;
    const bf16* r1 = oP + ((sbase + 1) * 128 + row) * 64;
    bf16* dst = ob + ((size_t)(b * T_ + t)) * D_ + h * HD_;
#pragma unroll
    for (int g = 0; g < 8; ++g) {
        bf16x8 a = *(const bf16x8*)&r0[g * 8];
        bf16x8 c = *(const bf16x8*)&r1[g * 8];
        bf16x8 o;
#pragma unroll
        for (int j = 0; j < 8; ++j)
            o[j] = (bf16)((float)a[j] * w0 + (float)c[j] * w1);
        *(bf16x8*)&dst[g * 8] = o;
    }
}

// ---------------- launch ----------------
extern "C" void kernel_launch(void* const* d_in, const int* in_sizes, int n_in,
                              void* d_out, int out_size, void* d_ws, size_t ws_size,
                              hipStream_t stream) {
    const float* x = (const float*)d_in[0];
    const float* w_qkv = (const float*)d_in[1];
    const float* w_proj = (const float*)d_in[2];
    const float* b_proj = (const float*)d_in[3];
    float* out = (float*)d_out;
    char* ws = (char*)d_ws;

    // ws layout (40 MB total, aliased by liveness):
    bf16* xb = (bf16*)(ws);                 // [4096][1024]  8MB ; dead after GEMM1
    bf16* ob = (bf16*)(ws);                 // alias: attn out (written after xb dead)
    bf16* wqkvt = (bf16*)(ws + 8388608);    // [3072][1024]  6MB ; dead after GEMM1
    bf16* vtbuf = (bf16*)(ws + 8388608);    // alias: [bh][64][T] 8MB
    bf16* qbuf = (bf16*)(ws + 16777216);    // [bh][T][64]   8MB
    bf16* wprojt = (bf16*)(ws + 16777216);  // alias: [1024][1024] 2MB (after attn)
    bf16* kbuf = (bf16*)(ws + 25165824);    // [bh][T][64]   8MB
    bf16* vbuf = (bf16*)(ws + 33554432);    // [bh][T][64]   8MB ; dead after transpose_v
    bf16* oP = (bf16*)(ws + 33554432);      // alias: partial O [32][7][2][128][64] 7.34MB
    float2* mlP = (float2*)(ws + 33554432 + 7340032);  // [32][7][2][128] 448KB

    cast_f32_bf16<<<4096, 256, 0, stream>>>(x, xb, (B_ * T_ * D_) / 4);
    dim3 tb(32, 8);
    cast_transpose<<<dim3(3 * D_ / 32, D_ / 32), tb, 0, stream>>>(w_qkv, wqkvt, D_, 3 * D_);

    // GEMM1: 4096 x 3072 x 1024, block 128x128 -> grid 768 = 3 blocks/CU
    gemm_k<2, 2, 0><<<dim3((B_ * T_) / 128, (3 * D_) / 128), 256, 0, stream>>>(
        xb, wqkvt, B_ * T_, 3 * D_, D_, qbuf, kbuf, vbuf, nullptr, nullptr);

    transpose_v<<<dim3(T_ / 64, B_ * H_), 256, 0, stream>>>(vbuf, vtbuf);

    // attn: per bh 9 single-strips + 7*2 split segments = 23 blocks; x32 bh = 736
    attn_kernel<<<23 * 32, 256, 0, stream>>>(qbuf, kbuf, vtbuf, ob, oP, mlP);
    // merge: 32*7*128 rows / 256 = 112 blocks
    attn_merge<<<112, 256, 0, stream>>>(oP, mlP, ob);

    cast_transpose<<<dim3(D_ / 32, D_ / 32), tb, 0, stream>>>(w_proj, wprojt, D_, D_);

    // GEMM2: 4096 x 1024 x 1024, block 64x128 -> grid 512 = 2 blocks/CU
    gemm_k<1, 2, 1><<<dim3((B_ * T_) / 64, D_ / 128), 256, 0, stream>>>(
        ob, wprojt, B_ * T_, D_, D_, nullptr, nullptr, nullptr, b_proj, out);
}

// Round 13
// 118.563 us; speedup vs baseline: 1.1129x; 1.0668x over previous
//
#include <hip/hip_runtime.h>
#include <hip/hip_bf16.h>

// Fused causal MHA: qkv proj (V written pre-transposed) -> flash attention
// (kv-split) -> out proj. B=2 T=2048 D=1024 H=16 hd=64; softmax in log2 domain.

typedef __bf16 bf16;
typedef float f32x4 __attribute__((ext_vector_type(4)));
typedef float f32x16 __attribute__((ext_vector_type(16)));
typedef bf16 bf16x4 __attribute__((ext_vector_type(4)));
typedef bf16 bf16x8 __attribute__((ext_vector_type(8)));

#define B_ 2
#define T_ 2048
#define D_ 1024
#define H_ 16
#define HD_ 64
#define QSPLIT 9  // qt >= QSPLIT gets 2 kv-segments

__device__ __forceinline__ f32x16 mfma32(bf16x8 a, bf16x8 b, f32x16 c) {
    return __builtin_amdgcn_mfma_f32_32x32x16_bf16(a, b, c, 0, 0, 0);
}

// async global->LDS, 16B per lane (wave-uniform LDS base + lane*16)
__device__ __forceinline__ void gload16(void* l, const void* g) {
    __builtin_amdgcn_global_load_lds(
        (const __attribute__((address_space(1))) unsigned int*)g,
        (__attribute__((address_space(3))) unsigned int*)l, 16, 0, 0);
}

__device__ __forceinline__ f32x16 z16() {
    f32x16 v;
#pragma unroll
    for (int i = 0; i < 16; ++i) v[i] = 0.f;
    return v;
}

// ---------------- cast kernels ----------------
__global__ __launch_bounds__(256) void cast_f32_bf16(const float* __restrict__ in,
                                                     bf16* __restrict__ out, int n4) {
    int i = blockIdx.x * 256 + threadIdx.x;
    if (i < n4) {
        float4 v = ((const float4*)in)[i];
        bf16x4 o = { (bf16)v.x, (bf16)v.y, (bf16)v.z, (bf16)v.w };
        ((bf16x4*)out)[i] = o;
    }
}

// in [R][C] f32 -> out [C][R] bf16
__global__ __launch_bounds__(256) void cast_transpose(const float* __restrict__ in,
                                                      bf16* __restrict__ out, int R, int C) {
    __shared__ float tile[32][33];
    int cx = blockIdx.x * 32 + threadIdx.x;
    int r0 = blockIdx.y * 32;
#pragma unroll
    for (int j = 0; j < 32; j += 8)
        tile[threadIdx.y + j][threadIdx.x] = in[(size_t)(r0 + threadIdx.y + j) * C + cx];
    __syncthreads();
    int rx = r0 + threadIdx.x;
    int c0 = blockIdx.x * 32;
#pragma unroll
    for (int j = 0; j < 32; j += 8)
        out[(size_t)(c0 + threadIdx.y + j) * R + rx] = (bf16)tile[threadIdx.x][threadIdx.y + j];
}

// ---------------- GEMM: C[M,N] = A[M,K] * Bt[N,K]^T, 32x32x16 MFMA ----------------
// EPI 0: scatter q/k into [bh][T][64]; V written TRANSPOSED into vt [bh][64][T]
// (bf16x4 along t; lane-pairs cover full 64B lines -> L2 write-combines).
// EPI 1: +bias, f32 out.
template <int MW, int NWN, int EPI>
__global__ __launch_bounds__(256) void gemm_k(
    const bf16* __restrict__ A, const bf16* __restrict__ Bt,
    int M, int N, int K,
    bf16* __restrict__ qb, bf16* __restrict__ kb, bf16* __restrict__ vt,
    const float* __restrict__ bias, float* __restrict__ outf) {
    constexpr int BM = 64 * MW;
    constexpr int BN = 64 * NWN;
    __shared__ bf16 sA[BM * 64];
    __shared__ bf16 sB[BN * 64];
    const int tid = threadIdx.x;
    const int wave = tid >> 6, lane = tid & 63;
    const int ln = lane & 31, hi = lane >> 5;
    const int wr = (wave >> 1) * (32 * MW);
    const int wc = (wave & 1) * (32 * NWN);
    const int m0 = blockIdx.x * BM, n0 = blockIdx.y * BN;

    f32x16 acc[MW][NWN];
#pragma unroll
    for (int mi = 0; mi < MW; ++mi)
#pragma unroll
        for (int ni = 0; ni < NWN; ++ni) acc[mi][ni] = z16();

    for (int k0 = 0; k0 < K; k0 += 64) {
        __syncthreads();
#pragma unroll
        for (int j = 0; j < 2 * MW; ++j) {
            int c = tid + 256 * j;
            int r = c >> 3, g = (c & 7) ^ (r & 7);
            gload16(&sA[c * 8], A + (size_t)(m0 + r) * K + k0 + 8 * g);
        }
#pragma unroll
        for (int j = 0; j < 2 * NWN; ++j) {
            int c = tid + 256 * j;
            int r = c >> 3, g = (c & 7) ^ (r & 7);
            gload16(&sB[c * 8], Bt + (size_t)(n0 + r) * K + k0 + 8 * g);
        }
        __syncthreads();
#pragma unroll
        for (int s = 0; s < 4; ++s) {
            bf16x8 av[MW], bv[NWN];
#pragma unroll
            for (int mi = 0; mi < MW; ++mi) {
                int r = wr + mi * 32 + ln;
                av[mi] = *(const bf16x8*)((const char*)sA + r * 128 +
                                          ((((s << 1) | hi) ^ (r & 7)) << 4));
            }
#pragma unroll
            for (int ni = 0; ni < NWN; ++ni) {
                int r = wc + ni * 32 + ln;
                bv[ni] = *(const bf16x8*)((const char*)sB + r * 128 +
                                          ((((s << 1) | hi) ^ (r & 7)) << 4));
            }
#pragma unroll
            for (int mi = 0; mi < MW; ++mi)
#pragma unroll
                for (int ni = 0; ni < NWN; ++ni)
                    acc[mi][ni] = mfma32(av[mi], bv[ni], acc[mi][ni]);
        }
    }

    // epilogue: C/D layout col=lane&31, row=(r&3)+8*(r>>2)+4*hi
#pragma unroll
    for (int mi = 0; mi < MW; ++mi)
#pragma unroll
        for (int ni = 0; ni < NWN; ++ni) {
            int col = n0 + wc + ni * 32 + ln;
            if (EPI == 0) {
                int part = col >> 10, h = (col >> 6) & 15, d = col & 63;
                if (part == 2) {
                    // V: transposed scatter, bf16x4 along t (r&3 = consecutive t)
#pragma unroll
                    for (int g4 = 0; g4 < 4; ++g4) {
                        int row = m0 + wr + mi * 32 + 8 * g4 + 4 * hi;
                        int bb = row >> 11, tt = row & (T_ - 1);
                        bf16x4 w;
#pragma unroll
                        for (int j = 0; j < 4; ++j)
                            w[j] = (bf16)acc[mi][ni][4 * g4 + j];
                        *(bf16x4*)&vt[(((size_t)(bb * H_ + h) * HD_) + d) * T_ + tt] = w;
                    }
                } else {
                    bf16* dst = (part == 0) ? qb : kb;
#pragma unroll
                    for (int r = 0; r < 16; ++r) {
                        int row = m0 + wr + mi * 32 + (r & 3) + 8 * (r >> 2) + 4 * hi;
                        int bb = row >> 11, tt = row & (T_ - 1);
                        dst[((size_t)(bb * H_ + h) * T_ + tt) * HD_ + d] =
                            (bf16)acc[mi][ni][r];
                    }
                }
            } else {
#pragma unroll
                for (int r = 0; r < 16; ++r) {
                    int row = m0 + wr + mi * 32 + (r & 3) + 8 * (r >> 2) + 4 * hi;
                    outf[(size_t)row * N + col] = acc[mi][ni][r] + bias[col];
                }
            }
        }
}

// ---------------- flash attention: swapped-operand 32x32 MFMA + kv-split ------
// r10-exact body (best measured 49.4us): 2-buffer global_load_lds prefetch,
// ones-MFMA row-sum, max3 reduce, defer-max, plain __syncthreads.
__device__ __forceinline__ bf16x8 kread(const char* base, int row, int s, int hi) {
    int b = (row * 128 + s * 32 + hi * 16) ^ ((row & 7) << 4);
    return *(const bf16x8*)(base + b);
}
__device__ __forceinline__ bf16x8 vread(const char* base, int row, int s, int hi) {
    int sw = (row & 7) << 4;
    int b0 = (row * 128 + s * 32 + hi * 8) ^ sw;
    int b1 = (row * 128 + s * 32 + hi * 8 + 16) ^ sw;
    bf16x4 lo = *(const bf16x4*)(base + b0);
    bf16x4 hi4 = *(const bf16x4*)(base + b1);
    return __builtin_shufflevector(lo, hi4, 0, 1, 2, 3, 4, 5, 6, 7);
}

__global__ __launch_bounds__(256, 3) void attn_kernel(
    const bf16* __restrict__ qb, const bf16* __restrict__ kb,
    const bf16* __restrict__ vtb, bf16* __restrict__ ob,
    bf16* __restrict__ oP, float2* __restrict__ mlP) {
    __shared__ bf16 sK2[2][4096];  // [64 kv][64 hd], 128B rows, chunk-swizzled
    __shared__ bf16 sV2[2][4096];  // [64 d][64 kv], 128B rows, chunk-swizzled

    const int bid = blockIdx.x;
    const int bh = bid & 31;
    const int sid = bid >> 5;  // 0..22
    int qt, seg, t0, t1;
    if (sid < QSPLIT) {
        qt = sid; seg = -1; t0 = 0; t1 = 2 * qt + 2;
    } else {
        int idx = sid - QSPLIT;
        qt = QSPLIT + (idx >> 1);
        seg = idx & 1;
        if (seg == 0) { t0 = 0; t1 = qt + 1; }
        else          { t0 = qt + 1; t1 = 2 * qt + 2; }
    }
    const int b = bh >> 4, h = bh & 15;
    const int tid = threadIdx.x, wave = tid >> 6, lane = tid & 63;
    const int ln = lane & 31, hi = lane >> 5;
    const int qs = qt * 128 + wave * 32;
    const int qrow = qs + ln;

    const bf16* Qg = qb + (size_t)bh * (T_ * HD_);
    const bf16* Kg = kb + (size_t)bh * (T_ * HD_);
    const bf16* Vtg = vtb + (size_t)bh * (HD_ * T_);

    // Q fragments, scale 0.125*log2(e) folded in (softmax in log2 domain)
    bf16x8 qf[4];
#pragma unroll
    for (int s = 0; s < 4; ++s) {
        bf16x8 v = *(const bf16x8*)&Qg[(size_t)qrow * HD_ + s * 16 + hi * 8];
#pragma unroll
        for (int e = 0; e < 8; ++e) v[e] = (bf16)((float)v[e] * 0.1803368801f);
        qf[s] = v;
    }
    bf16x8 ones;
#pragma unroll
    for (int e = 0; e < 8; ++e) ones[e] = (bf16)1.0f;

    // staging geometry: linear chunk c -> row r=c>>3, source chunk g=(c&7)^(r&7)
    const int rr0 = tid >> 3;
    const int gg = ((tid & 7) ^ (rr0 & 7)) * 8;

    // prologue: stage tile t0 into buffer 0 via async DMA
    {
        int kv0 = t0 * 64;
        gload16(&sK2[0][tid * 8], Kg + (size_t)(kv0 + rr0) * HD_ + gg);
        gload16(&sK2[0][(tid + 256) * 8], Kg + (size_t)(kv0 + rr0 + 32) * HD_ + gg);
        gload16(&sV2[0][tid * 8], Vtg + (size_t)rr0 * T_ + kv0 + gg);
        gload16(&sV2[0][(tid + 256) * 8], Vtg + (size_t)(rr0 + 32) * T_ + kv0 + gg);
    }
    __syncthreads();

    const float NINF = -__builtin_inff();
    f32x16 oA = z16(), oB = z16();
    float mR = NINF, lR = 0.f;
    int cur = 0;

    for (int t = t0; t < t1; ++t) {
        if ((t + 1) < t1) {  // async prefetch of next tile
            int kv0 = (t + 1) * 64;
            bf16* kd = sK2[cur ^ 1];
            bf16* vd = sV2[cur ^ 1];
            gload16(&kd[tid * 8], Kg + (size_t)(kv0 + rr0) * HD_ + gg);
            gload16(&kd[(tid + 256) * 8], Kg + (size_t)(kv0 + rr0 + 32) * HD_ + gg);
            gload16(&vd[tid * 8], Vtg + (size_t)rr0 * T_ + kv0 + gg);
            gload16(&vd[(tid + 256) * 8], Vtg + (size_t)(rr0 + 32) * T_ + kv0 + gg);
        }

        if (64 * t <= qs + 31) {  // wave not fully masked for this tile
            const char* kbase = (const char*)sK2[cur];
            const char* vbase = (const char*)sV2[cur];

            f32x16 p0 = z16(), p1 = z16();
            __builtin_amdgcn_s_setprio(1);
#pragma unroll
            for (int s = 0; s < 4; ++s) {
                bf16x8 a0 = kread(kbase, ln, s, hi);
                bf16x8 a1 = kread(kbase, ln + 32, s, hi);
                p0 = mfma32(a0, qf[s], p0);
                p1 = mfma32(a1, qf[s], p1);
            }
            __builtin_amdgcn_s_setprio(0);

            if (64 * t + 63 > qs) {  // diagonal tile: causal mask
                int kvb = 64 * t + 4 * hi;
#pragma unroll
                for (int r = 0; r < 16; ++r) {
                    int kvr = kvb + (r & 3) + 8 * (r >> 2);
                    if (kvr > qrow) p0[r] = NINF;
                    if (kvr + 32 > qrow) p1[r] = NINF;
                }
            }

            // max reduce: max3-shaped (16 fused ops)
            float mx0 = NINF, mx1 = NINF, mx2 = NINF, mx3 = NINF;
#pragma unroll
            for (int r = 0; r < 16; r += 4) {
                mx0 = fmaxf(fmaxf(p0[r], p1[r]), mx0);
                mx1 = fmaxf(fmaxf(p0[r + 1], p1[r + 1]), mx1);
                mx2 = fmaxf(fmaxf(p0[r + 2], p1[r + 2]), mx2);
                mx3 = fmaxf(fmaxf(p0[r + 3], p1[r + 3]), mx3);
            }
            float pm = fmaxf(fmaxf(mx0, mx1), fmaxf(mx2, mx3));
            pm = fmaxf(pm, __shfl_xor(pm, 32));

            // T13 defer-max: rescale only when the running max grows materially
            if (__any(pm > mR + 8.f)) {
                float mnew = fmaxf(mR, pm);
                float fac = exp2f(mR - mnew);
                lR *= fac;
#pragma unroll
                for (int r = 0; r < 16; ++r) { oA[r] *= fac; oB[r] *= fac; }
                mR = mnew;
            }

            // exp2 -> bf16 pack (row-sum via ones-MFMA below)
            bf16x8 pa0, pa1, pa2, pa3;
#pragma unroll
            for (int e = 0; e < 8; ++e) {
                pa0[e] = (bf16)exp2f(p0[e] - mR);
                pa1[e] = (bf16)exp2f(p0[8 + e] - mR);
                pa2[e] = (bf16)exp2f(p1[e] - mR);
                pa3[e] = (bf16)exp2f(p1[8 + e] - mR);
            }

            __builtin_amdgcn_s_setprio(1);
            // row-sum: D = ones * P^T -> every D row = column sums of P
            f32x16 sacc = mfma32(ones, pa0, z16());
            sacc = mfma32(ones, pa1, sacc);
            sacc = mfma32(ones, pa2, sacc);
            sacc = mfma32(ones, pa3, sacc);
#pragma unroll
            for (int s = 0; s < 4; ++s) {
                bf16x8 pas = (s == 0) ? pa0 : (s == 1) ? pa1 : (s == 2) ? pa2 : pa3;
                oA = mfma32(vread(vbase, ln, s, hi), pas, oA);
                oB = mfma32(vread(vbase, ln + 32, s, hi), pas, oB);
            }
            __builtin_amdgcn_s_setprio(0);
            lR += sacc[0];  // full 64-kv row sum (MFMA reduced across wave)
        }

        __syncthreads();  // drains prefetch DMA + LDS reads; flip buffers
        cur ^= 1;
    }

    if (seg < 0) {
        // final: normalized write to ob [B][T][H*64]
        float inv = 1.f / lR;
        bf16* orow = ob + ((size_t)(b * T_ + qrow)) * D_ + h * HD_;
#pragma unroll
        for (int g = 0; g < 4; ++g) {
            bf16x4 w, w2;
#pragma unroll
            for (int j = 0; j < 4; ++j) {
                w[j] = (bf16)(oA[4 * g + j] * inv);
                w2[j] = (bf16)(oB[4 * g + j] * inv);
            }
            *(bf16x4*)&orow[4 * hi + 8 * g] = w;
            *(bf16x4*)&orow[32 + 4 * hi + 8 * g] = w2;
        }
    } else {
        // partial: unnormalized O + (m,l)
        int row = wave * 32 + ln;
        size_t sbase = (((size_t)bh * (16 - QSPLIT) + (qt - QSPLIT)) * 2 + seg);
        bf16* prow = oP + (sbase * 128 + row) * 64;
#pragma unroll
        for (int g = 0; g < 4; ++g) {
            bf16x4 w, w2;
#pragma unroll
            for (int j = 0; j < 4; ++j) {
                w[j] = (bf16)oA[4 * g + j];
                w2[j] = (bf16)oB[4 * g + j];
            }
            *(bf16x4*)&prow[4 * hi + 8 * g] = w;
            *(bf16x4*)&prow[32 + 4 * hi + 8 * g] = w2;
        }
        if (hi == 0) mlP[sbase * 128 + row] = make_float2(mR, lR);
    }
}

// merge 2 kv-segments per split q-strip: one thread per q-row
__global__ __launch_bounds__(256) void attn_merge(
    const bf16* __restrict__ oP, const float2* __restrict__ mlP,
    bf16* __restrict__ ob) {
    constexpr int NQS = 16 - QSPLIT;  // 7
    int gid = blockIdx.x * 256 + threadIdx.x;  // 32*NQS*128 total
    int bh = gid / (NQS * 128);
    int rem = gid - bh * (NQS * 128);
    int qi = rem >> 7, row = rem & 127;
    int b = bh >> 4, h = bh & 15;
    int t = (QSPLIT + qi) * 128 + row;
    size_t sbase = ((size_t)bh * NQS + qi) * 2;
    float2 ml0 = mlP[(sbase + 0) * 128 + row];
    float2 ml1 = mlP[(sbase + 1) * 128 + row];
    float ms = fmaxf(ml0.x, ml1.x);
    float w0 = exp2f(ml0.x - ms), w1 = exp2f(ml1.x - ms);
    float inv = 1.f / (ml0.y * w0 + ml1.y * w1);
    w0 *= inv; w1 *= inv;
    const bf16* r0 = oP + ((sbase + 0) * 128 + row) * 64;
    const bf16* r1 = oP + ((sbase + 1) * 128 + row) * 64;
    bf16* dst = ob + ((size_t)(b * T_ + t)) * D_ + h * HD_;
#pragma unroll
    for (int g = 0; g < 8; ++g) {
        bf16x8 a = *(const bf16x8*)&r0[g * 8];
        bf16x8 c = *(const bf16x8*)&r1[g * 8];
        bf16x8 o;
#pragma unroll
        for (int j = 0; j < 8; ++j)
            o[j] = (bf16)((float)a[j] * w0 + (float)c[j] * w1);
        *(bf16x8*)&dst[g * 8] = o;
    }
}

// ---------------- launch ----------------
extern "C" void kernel_launch(void* const* d_in, const int* in_sizes, int n_in,
                              void* d_out, int out_size, void* d_ws, size_t ws_size,
                              hipStream_t stream) {
    const float* x = (const float*)d_in[0];
    const float* w_qkv = (const float*)d_in[1];
    const float* w_proj = (const float*)d_in[2];
    const float* b_proj = (const float*)d_in[3];
    float* out = (float*)d_out;
    char* ws = (char*)d_ws;

    // ws layout (40 MB total, aliased by liveness):
    bf16* xb = (bf16*)(ws);                  // [4096][1024]  8MB ; dead after GEMM1
    bf16* ob = (bf16*)(ws);                  // alias: attn out (written after xb dead)
    bf16* wqkvt = (bf16*)(ws + 8388608);     // [3072][1024]  6MB ; dead after GEMM1
    bf16* oP = (bf16*)(ws + 8388608);        // alias: partial O [32][7][2][128][64] 7.34MB
    float2* mlP = (float2*)(ws + 15728640);  // alias tail: [32][7][2][128] 448KB (<16.7M)
    bf16* qbuf = (bf16*)(ws + 16777216);     // [bh][T][64]   8MB ; dead after attn
    bf16* kbuf = (bf16*)(ws + 25165824);     // [bh][T][64]   8MB ; dead after attn
    bf16* wprojt = (bf16*)(ws + 25165824);   // alias: [1024][1024] 2MB (after attn)
    bf16* vtbuf = (bf16*)(ws + 33554432);    // [bh][64][T]   8MB (GEMM1 writes direct)

    cast_f32_bf16<<<4096, 256, 0, stream>>>(x, xb, (B_ * T_ * D_) / 4);
    dim3 tb(32, 8);
    cast_transpose<<<dim3(3 * D_ / 32, D_ / 32), tb, 0, stream>>>(w_qkv, wqkvt, D_, 3 * D_);

    // GEMM1: 4096 x 3072 x 1024, block 128x128 -> grid 768 = 3 blocks/CU.
    // V is scattered directly transposed into vtbuf (no transpose_v kernel).
    gemm_k<2, 2, 0><<<dim3((B_ * T_) / 128, (3 * D_) / 128), 256, 0, stream>>>(
        xb, wqkvt, B_ * T_, 3 * D_, D_, qbuf, kbuf, vtbuf, nullptr, nullptr);

    // attn: per bh 9 single-strips + 7*2 split segments = 23 blocks; x32 bh = 736
    attn_kernel<<<23 * 32, 256, 0, stream>>>(qbuf, kbuf, vtbuf, ob, oP, mlP);
    // merge: 32*7*128 rows / 256 = 112 blocks
    attn_merge<<<112, 256, 0, stream>>>(oP, mlP, ob);

    cast_transpose<<<dim3(D_ / 32, D_ / 32), tb, 0, stream>>>(w_proj, wprojt, D_, D_);

    // GEMM2: 4096 x 1024 x 1024, block 64x128 -> grid 512 = 2 blocks/CU
    gemm_k<1, 2, 1><<<dim3((B_ * T_) / 64, D_ / 128), 256, 0, stream>>>(
        ob, wprojt, B_ * T_, D_, D_, nullptr, nullptr, nullptr, b_proj, out);
}

// Round 14
// 110.617 us; speedup vs baseline: 1.1928x; 1.0718x over previous
//
#include <hip/hip_runtime.h>
#include <hip/hip_bf16.h>

// Fused causal MHA: prep (cast+transposes, 1 kernel) -> qkv proj (V written
// pre-transposed) -> flash attention (kv-split, balanced) -> merge -> out proj.
// B=2 T=2048 D=1024 H=16 hd=64; softmax in log2 domain (0.125*log2e in Q).

typedef __bf16 bf16;
typedef float f32x4 __attribute__((ext_vector_type(4)));
typedef float f32x16 __attribute__((ext_vector_type(16)));
typedef bf16 bf16x4 __attribute__((ext_vector_type(4)));
typedef bf16 bf16x8 __attribute__((ext_vector_type(8)));

#define B_ 2
#define T_ 2048
#define D_ 1024
#define H_ 16
#define HD_ 64
#define QSPLIT 9  // qt >= QSPLIT has 2 kv-segments

__device__ __forceinline__ f32x16 mfma32(bf16x8 a, bf16x8 b, f32x16 c) {
    return __builtin_amdgcn_mfma_f32_32x32x16_bf16(a, b, c, 0, 0, 0);
}

// async global->LDS, 16B per lane (wave-uniform LDS base + lane*16)
__device__ __forceinline__ void gload16(void* l, const void* g) {
    __builtin_amdgcn_global_load_lds(
        (const __attribute__((address_space(1))) unsigned int*)g,
        (__attribute__((address_space(3))) unsigned int*)l, 16, 0, 0);
}

__device__ __forceinline__ f32x16 z16() {
    f32x16 v;
#pragma unroll
    for (int i = 0; i < 16; ++i) v[i] = 0.f;
    return v;
}

// ---------------- fused prep: cast x -> xb ; transpose-cast w_qkv, w_proj ----
// grid 8192: [0,4096) cast x (4 f32/thread); [4096,7168) w_qkv T (96x32 tiles);
// [7168,8192) w_proj T (32x32 tiles).
__global__ __launch_bounds__(256) void prep(
    const float* __restrict__ x, bf16* __restrict__ xb,
    const float* __restrict__ wqkv, bf16* __restrict__ wqkvt,
    const float* __restrict__ wproj, bf16* __restrict__ wprojt) {
    __shared__ float tile[32][33];
    const int bid = blockIdx.x;
    const int tid = threadIdx.x;
    if (bid < 4096) {
        int i = bid * 256 + tid;
        float4 v = ((const float4*)x)[i];
        bf16x4 o = { (bf16)v.x, (bf16)v.y, (bf16)v.z, (bf16)v.w };
        ((bf16x4*)xb)[i] = o;
        return;
    }
    const float* in;
    bf16* outp;
    int C, bx, by;
    if (bid < 4096 + 3072) {
        int r = bid - 4096;
        in = wqkv; outp = wqkvt; C = 3 * D_; bx = r % 96; by = r / 96;
    } else {
        int r = bid - 7168;
        in = wproj; outp = wprojt; C = D_; bx = r % 32; by = r / 32;
    }
    const int R = D_;
    const int tx = tid & 31, ty = tid >> 5;
    int cx = bx * 32 + tx;
    int r0 = by * 32;
#pragma unroll
    for (int j = 0; j < 32; j += 8)
        tile[ty + j][tx] = in[(size_t)(r0 + ty + j) * C + cx];
    __syncthreads();
    int rx = r0 + tx;
    int c0 = bx * 32;
#pragma unroll
    for (int j = 0; j < 32; j += 8)
        outp[(size_t)(c0 + ty + j) * R + rx] = (bf16)tile[tx][ty + j];
}

// ---------------- GEMM: C[M,N] = A[M,K] * Bt[N,K]^T, 32x32x16 MFMA ----------------
// EPI 0: scatter q/k into [bh][T][64]; V written TRANSPOSED into vt [bh][64][T].
// EPI 1: +bias, f32 out.
template <int MW, int NWN, int EPI>
__global__ __launch_bounds__(256) void gemm_k(
    const bf16* __restrict__ A, const bf16* __restrict__ Bt,
    int M, int N, int K,
    bf16* __restrict__ qb, bf16* __restrict__ kb, bf16* __restrict__ vt,
    const float* __restrict__ bias, float* __restrict__ outf) {
    constexpr int BM = 64 * MW;
    constexpr int BN = 64 * NWN;
    __shared__ bf16 sA[BM * 64];
    __shared__ bf16 sB[BN * 64];
    const int tid = threadIdx.x;
    const int wave = tid >> 6, lane = tid & 63;
    const int ln = lane & 31, hi = lane >> 5;
    const int wr = (wave >> 1) * (32 * MW);
    const int wc = (wave & 1) * (32 * NWN);
    const int m0 = blockIdx.x * BM, n0 = blockIdx.y * BN;

    f32x16 acc[MW][NWN];
#pragma unroll
    for (int mi = 0; mi < MW; ++mi)
#pragma unroll
        for (int ni = 0; ni < NWN; ++ni) acc[mi][ni] = z16();

    for (int k0 = 0; k0 < K; k0 += 64) {
        __syncthreads();
#pragma unroll
        for (int j = 0; j < 2 * MW; ++j) {
            int c = tid + 256 * j;
            int r = c >> 3, g = (c & 7) ^ (r & 7);
            gload16(&sA[c * 8], A + (size_t)(m0 + r) * K + k0 + 8 * g);
        }
#pragma unroll
        for (int j = 0; j < 2 * NWN; ++j) {
            int c = tid + 256 * j;
            int r = c >> 3, g = (c & 7) ^ (r & 7);
            gload16(&sB[c * 8], Bt + (size_t)(n0 + r) * K + k0 + 8 * g);
        }
        __syncthreads();
#pragma unroll
        for (int s = 0; s < 4; ++s) {
            bf16x8 av[MW], bv[NWN];
#pragma unroll
            for (int mi = 0; mi < MW; ++mi) {
                int r = wr + mi * 32 + ln;
                av[mi] = *(const bf16x8*)((const char*)sA + r * 128 +
                                          ((((s << 1) | hi) ^ (r & 7)) << 4));
            }
#pragma unroll
            for (int ni = 0; ni < NWN; ++ni) {
                int r = wc + ni * 32 + ln;
                bv[ni] = *(const bf16x8*)((const char*)sB + r * 128 +
                                          ((((s << 1) | hi) ^ (r & 7)) << 4));
            }
#pragma unroll
            for (int mi = 0; mi < MW; ++mi)
#pragma unroll
                for (int ni = 0; ni < NWN; ++ni)
                    acc[mi][ni] = mfma32(av[mi], bv[ni], acc[mi][ni]);
        }
    }

    // epilogue: C/D layout col=lane&31, row=(r&3)+8*(r>>2)+4*hi
#pragma unroll
    for (int mi = 0; mi < MW; ++mi)
#pragma unroll
        for (int ni = 0; ni < NWN; ++ni) {
            int col = n0 + wc + ni * 32 + ln;
            if (EPI == 0) {
                int part = col >> 10, h = (col >> 6) & 15, d = col & 63;
                if (part == 2) {
                    // V: transposed scatter, bf16x4 along t (r&3 = consecutive t)
#pragma unroll
                    for (int g4 = 0; g4 < 4; ++g4) {
                        int row = m0 + wr + mi * 32 + 8 * g4 + 4 * hi;
                        int bb = row >> 11, tt = row & (T_ - 1);
                        bf16x4 w;
#pragma unroll
                        for (int j = 0; j < 4; ++j)
                            w[j] = (bf16)acc[mi][ni][4 * g4 + j];
                        *(bf16x4*)&vt[(((size_t)(bb * H_ + h) * HD_) + d) * T_ + tt] = w;
                    }
                } else {
                    bf16* dst = (part == 0) ? qb : kb;
#pragma unroll
                    for (int r = 0; r < 16; ++r) {
                        int row = m0 + wr + mi * 32 + (r & 3) + 8 * (r >> 2) + 4 * hi;
                        int bb = row >> 11, tt = row & (T_ - 1);
                        dst[((size_t)(bb * H_ + h) * T_ + tt) * HD_ + d] =
                            (bf16)acc[mi][ni][r];
                    }
                }
            } else {
#pragma unroll
                for (int r = 0; r < 16; ++r) {
                    int row = m0 + wr + mi * 32 + (r & 3) + 8 * (r >> 2) + 4 * hi;
                    outf[(size_t)row * N + col] = acc[mi][ni][r] + bias[col];
                }
            }
        }
}

// ---------------- flash attention: swapped-operand 32x32 MFMA + kv-split ------
// r10-exact body (best measured). sid decoded via length-balanced tables so
// dispatch rounds mix long/short segments (tail-flattening). Split seg0 writes
// UNNORMALIZED rows into ob (fixed by merge); seg1 -> oP.
static __device__ const signed char QT_T[23] = {
    8, 7, 15, 15, 14, 14, 6, 13, 10, 10, 5, 11, 11, 12, 12, 13,
    0, 1, 2, 3, 4, 9, 9};
static __device__ const signed char SEG_T[23] = {
    -1, -1, 0, 1, 0, 1, -1, 0, 0, 1, -1, 0, 1, 0, 1, 1,
    -1, -1, -1, -1, -1, 0, 1};

__device__ __forceinline__ bf16x8 kread(const char* base, int row, int s, int hi) {
    int b = (row * 128 + s * 32 + hi * 16) ^ ((row & 7) << 4);
    return *(const bf16x8*)(base + b);
}
__device__ __forceinline__ bf16x8 vread(const char* base, int row, int s, int hi) {
    int sw = (row & 7) << 4;
    int b0 = (row * 128 + s * 32 + hi * 8) ^ sw;
    int b1 = (row * 128 + s * 32 + hi * 8 + 16) ^ sw;
    bf16x4 lo = *(const bf16x4*)(base + b0);
    bf16x4 hi4 = *(const bf16x4*)(base + b1);
    return __builtin_shufflevector(lo, hi4, 0, 1, 2, 3, 4, 5, 6, 7);
}

__global__ __launch_bounds__(256, 3) void attn_kernel(
    const bf16* __restrict__ qb, const bf16* __restrict__ kb,
    const bf16* __restrict__ vtb, bf16* __restrict__ ob,
    bf16* __restrict__ oP, float2* __restrict__ mlP) {
    __shared__ bf16 sK2[2][4096];  // [64 kv][64 hd], 128B rows, chunk-swizzled
    __shared__ bf16 sV2[2][4096];  // [64 d][64 kv], 128B rows, chunk-swizzled

    const int bid = blockIdx.x;
    const int bh = bid & 31;
    const int sid = bid >> 5;  // 0..22
    const int qt = QT_T[sid];
    const int seg = SEG_T[sid];
    int t0, t1;
    if (seg < 0)       { t0 = 0;      t1 = 2 * qt + 2; }
    else if (seg == 0) { t0 = 0;      t1 = qt + 1; }
    else               { t0 = qt + 1; t1 = 2 * qt + 2; }
    const int b = bh >> 4, h = bh & 15;
    const int tid = threadIdx.x, wave = tid >> 6, lane = tid & 63;
    const int ln = lane & 31, hi = lane >> 5;
    const int qs = qt * 128 + wave * 32;
    const int qrow = qs + ln;

    const bf16* Qg = qb + (size_t)bh * (T_ * HD_);
    const bf16* Kg = kb + (size_t)bh * (T_ * HD_);
    const bf16* Vtg = vtb + (size_t)bh * (HD_ * T_);

    // Q fragments, scale 0.125*log2(e) folded in (softmax in log2 domain)
    bf16x8 qf[4];
#pragma unroll
    for (int s = 0; s < 4; ++s) {
        bf16x8 v = *(const bf16x8*)&Qg[(size_t)qrow * HD_ + s * 16 + hi * 8];
#pragma unroll
        for (int e = 0; e < 8; ++e) v[e] = (bf16)((float)v[e] * 0.1803368801f);
        qf[s] = v;
    }
    bf16x8 ones;
#pragma unroll
    for (int e = 0; e < 8; ++e) ones[e] = (bf16)1.0f;

    // staging geometry: linear chunk c -> row r=c>>3, source chunk g=(c&7)^(r&7)
    const int rr0 = tid >> 3;
    const int gg = ((tid & 7) ^ (rr0 & 7)) * 8;

    // prologue: stage tile t0 into buffer 0 via async DMA
    {
        int kv0 = t0 * 64;
        gload16(&sK2[0][tid * 8], Kg + (size_t)(kv0 + rr0) * HD_ + gg);
        gload16(&sK2[0][(tid + 256) * 8], Kg + (size_t)(kv0 + rr0 + 32) * HD_ + gg);
        gload16(&sV2[0][tid * 8], Vtg + (size_t)rr0 * T_ + kv0 + gg);
        gload16(&sV2[0][(tid + 256) * 8], Vtg + (size_t)(rr0 + 32) * T_ + kv0 + gg);
    }
    __syncthreads();

    const float NINF = -__builtin_inff();
    f32x16 oA = z16(), oB = z16();
    float mR = NINF, lR = 0.f;
    int cur = 0;

    for (int t = t0; t < t1; ++t) {
        if ((t + 1) < t1) {  // async prefetch of next tile
            int kv0 = (t + 1) * 64;
            bf16* kd = sK2[cur ^ 1];
            bf16* vd = sV2[cur ^ 1];
            gload16(&kd[tid * 8], Kg + (size_t)(kv0 + rr0) * HD_ + gg);
            gload16(&kd[(tid + 256) * 8], Kg + (size_t)(kv0 + rr0 + 32) * HD_ + gg);
            gload16(&vd[tid * 8], Vtg + (size_t)rr0 * T_ + kv0 + gg);
            gload16(&vd[(tid + 256) * 8], Vtg + (size_t)(rr0 + 32) * T_ + kv0 + gg);
        }

        if (64 * t <= qs + 31) {  // wave not fully masked for this tile
            const char* kbase = (const char*)sK2[cur];
            const char* vbase = (const char*)sV2[cur];

            f32x16 p0 = z16(), p1 = z16();
            __builtin_amdgcn_s_setprio(1);
#pragma unroll
            for (int s = 0; s < 4; ++s) {
                bf16x8 a0 = kread(kbase, ln, s, hi);
                bf16x8 a1 = kread(kbase, ln + 32, s, hi);
                p0 = mfma32(a0, qf[s], p0);
                p1 = mfma32(a1, qf[s], p1);
            }
            __builtin_amdgcn_s_setprio(0);

            if (64 * t + 63 > qs) {  // diagonal tile: causal mask
                int kvb = 64 * t + 4 * hi;
#pragma unroll
                for (int r = 0; r < 16; ++r) {
                    int kvr = kvb + (r & 3) + 8 * (r >> 2);
                    if (kvr > qrow) p0[r] = NINF;
                    if (kvr + 32 > qrow) p1[r] = NINF;
                }
            }

            // max reduce: max3-shaped (16 fused ops)
            float mx0 = NINF, mx1 = NINF, mx2 = NINF, mx3 = NINF;
#pragma unroll
            for (int r = 0; r < 16; r += 4) {
                mx0 = fmaxf(fmaxf(p0[r], p1[r]), mx0);
                mx1 = fmaxf(fmaxf(p0[r + 1], p1[r + 1]), mx1);
                mx2 = fmaxf(fmaxf(p0[r + 2], p1[r + 2]), mx2);
                mx3 = fmaxf(fmaxf(p0[r + 3], p1[r + 3]), mx3);
            }
            float pm = fmaxf(fmaxf(mx0, mx1), fmaxf(mx2, mx3));
            pm = fmaxf(pm, __shfl_xor(pm, 32));

            // T13 defer-max: rescale only when the running max grows materially
            if (__any(pm > mR + 8.f)) {
                float mnew = fmaxf(mR, pm);
                float fac = exp2f(mR - mnew);
                lR *= fac;
#pragma unroll
                for (int r = 0; r < 16; ++r) { oA[r] *= fac; oB[r] *= fac; }
                mR = mnew;
            }

            // exp2 -> bf16 pack (row-sum via ones-MFMA below)
            bf16x8 pa0, pa1, pa2, pa3;
#pragma unroll
            for (int e = 0; e < 8; ++e) {
                pa0[e] = (bf16)exp2f(p0[e] - mR);
                pa1[e] = (bf16)exp2f(p0[8 + e] - mR);
                pa2[e] = (bf16)exp2f(p1[e] - mR);
                pa3[e] = (bf16)exp2f(p1[8 + e] - mR);
            }

            __builtin_amdgcn_s_setprio(1);
            // row-sum: D = ones * P^T -> every D row = column sums of P
            f32x16 sacc = mfma32(ones, pa0, z16());
            sacc = mfma32(ones, pa1, sacc);
            sacc = mfma32(ones, pa2, sacc);
            sacc = mfma32(ones, pa3, sacc);
#pragma unroll
            for (int s = 0; s < 4; ++s) {
                bf16x8 pas = (s == 0) ? pa0 : (s == 1) ? pa1 : (s == 2) ? pa2 : pa3;
                oA = mfma32(vread(vbase, ln, s, hi), pas, oA);
                oB = mfma32(vread(vbase, ln + 32, s, hi), pas, oB);
            }
            __builtin_amdgcn_s_setprio(0);
            lR += sacc[0];  // full 64-kv row sum (MFMA reduced across wave)
        }

        __syncthreads();  // drains prefetch DMA + LDS reads; flip buffers
        cur ^= 1;
    }

    if (seg < 0) {
        // final: normalized write to ob [B][T][H*64]
        float inv = 1.f / lR;
        bf16* orow = ob + ((size_t)(b * T_ + qrow)) * D_ + h * HD_;
#pragma unroll
        for (int g = 0; g < 4; ++g) {
            bf16x4 w, w2;
#pragma unroll
            for (int j = 0; j < 4; ++j) {
                w[j] = (bf16)(oA[4 * g + j] * inv);
                w2[j] = (bf16)(oB[4 * g + j] * inv);
            }
            *(bf16x4*)&orow[4 * hi + 8 * g] = w;
            *(bf16x4*)&orow[32 + 4 * hi + 8 * g] = w2;
        }
    } else {
        // partial: unnormalized O (+ m,l). seg0 -> ob rows (merge fixes them);
        // seg1 -> oP [32][7][128][64].
        int row = wave * 32 + ln;
        bf16* prow;
        if (seg == 0) {
            prow = ob + ((size_t)(b * T_ + qrow)) * D_ + h * HD_;
        } else {
            size_t sbase = (size_t)bh * (16 - QSPLIT) + (qt - QSPLIT);
            prow = oP + (sbase * 128 + row) * 64;
        }
#pragma unroll
        for (int g = 0; g < 4; ++g) {
            bf16x4 w, w2;
#pragma unroll
            for (int j = 0; j < 4; ++j) {
                w[j] = (bf16)oA[4 * g + j];
                w2[j] = (bf16)oB[4 * g + j];
            }
            *(bf16x4*)&prow[4 * hi + 8 * g] = w;
            *(bf16x4*)&prow[32 + 4 * hi + 8 * g] = w2;
        }
        if (hi == 0)
            mlP[(((size_t)bh * (16 - QSPLIT) + (qt - QSPLIT)) * 2 + seg) * 128 + row] =
                make_float2(mR, lR);
    }
}

// merge 2 kv-segments per split q-strip: one thread per q-row.
// seg0 partial lives in ob (unnormalized); seg1 in oP. Result -> ob normalized.
__global__ __launch_bounds__(256) void attn_merge(
    const bf16* __restrict__ oP, const float2* __restrict__ mlP,
    bf16* __restrict__ ob) {
    constexpr int NQS = 16 - QSPLIT;  // 7
    int gid = blockIdx.x * 256 + threadIdx.x;  // 32*NQS*128 total
    int bh = gid / (NQS * 128);
    int rem = gid - bh * (NQS * 128);
    int qi = rem >> 7, row = rem & 127;
    int b = bh >> 4, h = bh & 15;
    int t = (QSPLIT + qi) * 128 + row;
    size_t sbase = (size_t)bh * NQS + qi;
    float2 ml0 = mlP[(sbase * 2 + 0) * 128 + row];
    float2 ml1 = mlP[(sbase * 2 + 1) * 128 + row];
    float ms = fmaxf(ml0.x, ml1.x);
    float w0 = exp2f(ml0.x - ms), w1 = exp2f(ml1.x - ms);
    float inv = 1.f / (ml0.y * w0 + ml1.y * w1);
    w0 *= inv; w1 *= inv;
    bf16* dst = ob + ((size_t)(b * T_ + t)) * D_ + h * HD_;  // holds seg0 partial
    const bf16* r1 = oP + (sbase * 128 + row) * 64;
#pragma unroll
    for (int g = 0; g < 8; ++g) {
        bf16x8 a = *(const bf16x8*)&dst[g * 8];
        bf16x8 c = *(const bf16x8*)&r1[g * 8];
        bf16x8 o;
#pragma unroll
        for (int j = 0; j < 8; ++j)
            o[j] = (bf16)((float)a[j] * w0 + (float)c[j] * w1);
        *(bf16x8*)&dst[g * 8] = o;
    }
}

// ---------------- launch ----------------
extern "C" void kernel_launch(void* const* d_in, const int* in_sizes, int n_in,
                              void* d_out, int out_size, void* d_ws, size_t ws_size,
                              hipStream_t stream) {
    const float* x = (const float*)d_in[0];
    const float* w_qkv = (const float*)d_in[1];
    const float* w_proj = (const float*)d_in[2];
    const float* b_proj = (const float*)d_in[3];
    float* out = (float*)d_out;
    char* ws = (char*)d_ws;

    // ws layout (40 MB total, aliased by liveness):
    bf16* xb = (bf16*)(ws);                  // [4096][1024] 8MB ; dead after GEMM1
    bf16* ob = (bf16*)(ws);                  // alias: attn out (written after xb dead)
    bf16* wqkvt = (bf16*)(ws + 8388608);     // [3072][1024] 6MB ; dead after GEMM1
    bf16* oP = (bf16*)(ws + 8388608);        // alias: seg1 partials [32][7][128][64] 3.67MB
    float2* mlP = (float2*)(ws + 12058624);  // alias: [32][7][2][128] 448KB (ends 12.5M)
    bf16* wprojt = (bf16*)(ws + 14680064);   // [1024][1024] 2MB, prep->GEMM2, NO alias
    bf16* qbuf = (bf16*)(ws + 16777216);     // [bh][T][64]  8MB
    bf16* kbuf = (bf16*)(ws + 25165824);     // [bh][T][64]  8MB
    bf16* vtbuf = (bf16*)(ws + 33554432);    // [bh][64][T]  8MB (GEMM1 writes direct)

    // prep: cast x + transpose-cast w_qkv + transpose-cast w_proj (1 kernel)
    prep<<<8192, 256, 0, stream>>>(x, xb, w_qkv, wqkvt, w_proj, wprojt);

    // GEMM1: 4096 x 3072 x 1024, block 128x128 -> grid 768 = 3 blocks/CU.
    gemm_k<2, 2, 0><<<dim3((B_ * T_) / 128, (3 * D_) / 128), 256, 0, stream>>>(
        xb, wqkvt, B_ * T_, 3 * D_, D_, qbuf, kbuf, vtbuf, nullptr, nullptr);

    // attn: 23 length-balanced segments per bh x 32 bh = 736 blocks
    attn_kernel<<<23 * 32, 256, 0, stream>>>(qbuf, kbuf, vtbuf, ob, oP, mlP);
    // merge: 32*7*128 rows / 256 = 112 blocks
    attn_merge<<<112, 256, 0, stream>>>(oP, mlP, ob);

    // GEMM2: 4096 x 1024 x 1024, block 64x128 -> grid 512 = 2 blocks/CU
    gemm_k<1, 2, 1><<<dim3((B_ * T_) / 64, D_ / 128), 256, 0, stream>>>(
        ob, wprojt, B_ * T_, D_, D_, nullptr, nullptr, nullptr, b_proj, out);
}